// Round 6
// baseline (698.645 us; speedup 1.0000x reference)
//
#include <hip/hip_runtime.h>

#define N_NODES 100000
#define N_EDGES 600000
#define H 128
#define G_NUM 64
#define LN_EPS 1e-5f

// LDS bf16 row stride (conflict-free b128 frag reads)
#define WSTR 136

#define NTILES ((N_NODES + 63) / 64)     // 1563

#define SCAN_CHUNK 1024
#define SCAN_NB ((N_NODES + SCAN_CHUNK - 1) / SCAN_CHUNK)   // 98
#define HIST_NB ((N_EDGES + 255) / 256)                      // 2344
#define CVT_NB ((N_NODES * H / 8 + 255) / 256)               // 6250
#define FILL_NB ((N_EDGES + 255) / 256)                      // 2344
#define WT_NB ((3 * 16384 + 255) / 256)                      // 192

// edges per LDS chunk in gather; block edge count ~ Binom(E,64/N): mean 384,
// sd ~20 -> 1536 is mean+57sd; chunk loop is the correctness fallback anyway.
#define EBUF 1536

// ws layout (ints): gstat 512 | deg N | off N+1 | cursor N | csr E |
//                   blksum | WT (3*16k bf16) | [nbf (N*H bf16)] | h0 (N*H bf16)
#define WT_IOFF   900612
#define NBF_IOFF  925192                     // 16B-aligned
#define H0_BF_IOFF (NBF_IOFF + N_NODES * (H / 2))   // h0 after nbf (bf path)
#define NEEDED_BF  ((size_t)(H0_BF_IOFF + N_NODES * (H / 2)) * 4)     // ~54.9MB

typedef __attribute__((ext_vector_type(8))) short short8;
typedef __attribute__((ext_vector_type(4))) float floatx4;

__device__ __forceinline__ unsigned short f2bf(float x) {   // RNE fp32->bf16
    unsigned int u = __float_as_uint(x);
    u += 0x7fffu + ((u >> 16) & 1u);
    return (unsigned short)(u >> 16);
}

// ---------------------------------------------------------------------------
// CSR hist + bf16 node staging in SPLIT-PAIR layout:
//   nbf[n*64 + c] = bf16(x[n][c]) | bf16(x[n][c+64])<<16   (c in [0,64))
// so the gather's lane-c dword feeds LDS adds at banks c and c+64 (2-way, free).
// ---------------------------------------------------------------------------
__global__ __launch_bounds__(256) void hist_cvt_kernel(
    const int* __restrict__ ei, int* __restrict__ deg,
    const float* __restrict__ node, unsigned int* __restrict__ node_bf)
{
    int gb = blockIdx.x;
    if (gb < HIST_NB) {
        int e = gb * 256 + threadIdx.x;
        if (e >= N_EDGES) return;
        atomicAdd(&deg[ei[N_EDGES + e]], 1);
    } else {
        int i = (gb - HIST_NB) * 256 + threadIdx.x;   // uint4 index, N*16 total
        if (i >= N_NODES * 16) return;
        int n = i >> 4;
        int c0 = (i & 15) * 4;
        const float4 a = *(const float4*)&node[(size_t)n * H + c0];
        const float4 b = *(const float4*)&node[(size_t)n * H + 64 + c0];
        uint4 p;
        p.x = (unsigned)f2bf(a.x) | ((unsigned)f2bf(b.x) << 16);
        p.y = (unsigned)f2bf(a.y) | ((unsigned)f2bf(b.y) << 16);
        p.z = (unsigned)f2bf(a.z) | ((unsigned)f2bf(b.z) << 16);
        p.w = (unsigned)f2bf(a.w) | ((unsigned)f2bf(b.w) << 16);
        ((uint4*)node_bf)[i] = p;
    }
}

__global__ __launch_bounds__(256) void scan1_kernel(
    const int* __restrict__ deg, int* __restrict__ off,
    int* __restrict__ blksum)
{
    __shared__ int sA[256], sB[256];
    const int tid = threadIdx.x;
    const int base = blockIdx.x * SCAN_CHUNK + tid * 4;
    int v[4];
#pragma unroll
    for (int j = 0; j < 4; ++j) {
        int i = base + j;
        v[j] = (i < N_NODES) ? deg[i] : 0;
    }
    int tsum = v[0] + v[1] + v[2] + v[3];
    int* a = sA; int* b = sB;
    a[tid] = tsum;
    __syncthreads();
#pragma unroll
    for (int o = 1; o < 256; o <<= 1) {
        int t = a[tid] + ((tid >= o) ? a[tid - o] : 0);
        b[tid] = t;
        __syncthreads();
        int* tmp = a; a = b; b = tmp;
    }
    int run = a[tid] - tsum;
#pragma unroll
    for (int j = 0; j < 4; ++j) {
        int i = base + j;
        if (i < N_NODES) off[i] = run;
        run += v[j];
    }
    if (tid == 255) blksum[blockIdx.x] = a[255];
}

__global__ __launch_bounds__(256) void scan23_kernel(
    int* __restrict__ off, const int* __restrict__ blksum,
    int* __restrict__ cursor)
{
    __shared__ int sA[128], sB[128];
    const int tid = threadIdx.x;
    if (tid < 128) sA[tid] = (tid < SCAN_NB) ? blksum[tid] : 0;
    __syncthreads();
    int* a = sA; int* b = sB;
#pragma unroll
    for (int o = 1; o < 128; o <<= 1) {
        int t = 0;
        if (tid < 128) t = a[tid] + ((tid >= o) ? a[tid - o] : 0);
        __syncthreads();
        if (tid < 128) b[tid] = t;
        __syncthreads();
        int* tmp = a; a = b; b = tmp;
    }
    int excl = 0;
    if (tid < 128) excl = a[tid] - ((tid < SCAN_NB) ? blksum[tid] : 0);
    __syncthreads();
    if (tid < 128) sA[tid] = excl;
    __syncthreads();

    int i = blockIdx.x * 256 + tid;
    if (i < N_NODES) {
        int val = off[i] + sA[i >> 10];
        off[i] = val;
        cursor[i] = val;
    }
    if (i == 0) off[N_NODES] = N_EDGES;
}

// fill + FRAGMENT-PACKED bf16 weights (r11 layout), one dispatch.
__global__ __launch_bounds__(256) void fill_wt_kernel(
    const int* __restrict__ ei, int* __restrict__ cursor,
    int* __restrict__ csr,
    const float* __restrict__ W1, const float* __restrict__ W2,
    const float* __restrict__ W3, unsigned short* __restrict__ WT)
{
    int gb = blockIdx.x;
    if (gb < FILL_NB) {
        int e = gb * 256 + threadIdx.x;
        if (e >= N_EDGES) return;
        int dst = ei[N_EDGES + e];
        int pos = atomicAdd(&cursor[dst], 1);
        csr[pos] = ei[e];
    } else {
        int idx = (gb - FILL_NB) * 256 + threadIdx.x;
        if (idx >= 3 * 16384) return;
        int l = idx >> 14, r = idx & 16383;
        int frag = r >> 3, j = r & 7;
        int lane = frag & 63, ktnt = frag >> 6;
        int kt = ktnt & 3, nt = ktnt >> 2;
        int c = lane & 15, q = lane >> 4;
        int n = nt * 16 + c;
        int k = kt * 32 + q * 8 + j;
        const float* W = (l == 0) ? W1 : ((l == 1) ? W2 : W3);
        WT[l * 16384 + r] = f2bf(W[k * 128 + n]);
    }
}

// ---------------------------------------------------------------------------
// GATHER v2 — edge-parallel LDS accumulation (replaces chain-walking, which
// measured ~68 VALU inst/neighbor and 100us at 33% VALUBusy in r5).
// Block = 64 rows. hacc[64][128] f32 in LDS; all 4 waves stream the block's
// csr edges in batches of 8: uniform ds_read of packed (row<<18)|src ->
// 8 independent coalesced 256B row loads -> 16 ds_add_f32 (banks 2-way=free
// via split-pair layout). ~8-10 inst/edge, 8-deep loads, no divergence.
// ---------------------------------------------------------------------------
template <bool NBF>
__global__ __launch_bounds__(256) void gather_kernel(
    const float* __restrict__ node, const unsigned int* __restrict__ nbf,
    const int* __restrict__ off, const int* __restrict__ csr,
    const float* __restrict__ epsp, unsigned int* __restrict__ h0)
{
    __shared__ float hacc[64][H];      // 32 KB
    __shared__ int   scr[EBUF];        // 6 KB
    __shared__ int   s_off[65];
    // ~38.4 KB -> 4 blocks/CU (LDS-capped; hacc alone caps at 4)

    const int tid = threadIdx.x;
    const int w = tid >> 6, lane = tid & 63;
    const int row0 = blockIdx.x * 64;
    const float epsv = 1.0f + epsp[0];

    if (tid < 65) {
        int r = row0 + tid;
        s_off[tid] = off[(r > N_NODES) ? N_NODES : r];
    }

    // init hacc = (1+eps) * own  (split-pair source)
#pragma unroll
    for (int i = 0; i < 16; ++i) {
        int g = tid + 256 * i;           // u32-slot: row=g>>6, c=g&63
        int row = g >> 6, c = g & 63;
        int n = row0 + row;
        float x0 = 0.f, x1 = 0.f;
        if (n < N_NODES) {
            if constexpr (NBF) {
                unsigned int u = nbf[(size_t)n * 64 + c];
                x0 = __uint_as_float(u << 16);
                x1 = __uint_as_float(u & 0xffff0000u);
            } else {
                x0 = node[(size_t)n * H + c];
                x1 = node[(size_t)n * H + 64 + c];
            }
        }
        hacc[row][c]      = epsv * x0;
        hacc[row][64 + c] = epsv * x1;
    }
    __syncthreads();

    const int e_begin = s_off[0];
    const int cnt = s_off[64] - e_begin;

    for (int cb = 0; cb < cnt; cb += EBUF) {
        const int cwin = (cnt - cb < EBUF) ? (cnt - cb) : EBUF;
        // (a) fill scr with src ids (coalesced)
        for (int k = tid; k < cwin; k += 256) scr[k] = csr[e_begin + cb + k];
        __syncthreads();
        // (b) OR dst-row bits; each scr element has exactly one writer
        {
            const int r = tid >> 2, q = tid & 3;
            int klo = s_off[r] - e_begin;     if (klo < cb) klo = cb;
            int khi = s_off[r + 1] - e_begin; if (khi > cb + cwin) khi = cb + cwin;
            for (int k = klo + q; k < khi; k += 4)
                scr[k - cb] |= (r << 18);
        }
        __syncthreads();
        // (c) edge processing, wave-strided batches of 8
        const int cend = cb + cwin;
        for (int base = cb + w * 8; base < cend; base += 32) {
            const int m = (cend - base < 8) ? (cend - base) : 8;
            if (m == 8) {
                int nbv[8], rv[8];
#pragma unroll
                for (int j = 0; j < 8; ++j) {
                    int pk = __builtin_amdgcn_readfirstlane(scr[base - cb + j]);
                    nbv[j] = pk & 0x3FFFF;
                    rv[j] = pk >> 18;
                }
                float vx[8], vy[8];
#pragma unroll
                for (int j = 0; j < 8; ++j) {
                    if constexpr (NBF) {
                        unsigned int u = nbf[(size_t)nbv[j] * 64 + lane];
                        vx[j] = __uint_as_float(u << 16);
                        vy[j] = __uint_as_float(u & 0xffff0000u);
                    } else {
                        vx[j] = node[(size_t)nbv[j] * H + lane];
                        vy[j] = node[(size_t)nbv[j] * H + 64 + lane];
                    }
                }
#pragma unroll
                for (int j = 0; j < 8; ++j) {
                    atomicAdd(&hacc[rv[j]][lane], vx[j]);
                    atomicAdd(&hacc[rv[j]][64 + lane], vy[j]);
                }
            } else {
                for (int j = 0; j < m; ++j) {
                    int pk = __builtin_amdgcn_readfirstlane(scr[base - cb + j]);
                    int nb = pk & 0x3FFFF;
                    int r  = pk >> 18;
                    float x0, x1;
                    if constexpr (NBF) {
                        unsigned int u = nbf[(size_t)nb * 64 + lane];
                        x0 = __uint_as_float(u << 16);
                        x1 = __uint_as_float(u & 0xffff0000u);
                    } else {
                        x0 = node[(size_t)nb * H + lane];
                        x1 = node[(size_t)nb * H + 64 + lane];
                    }
                    atomicAdd(&hacc[r][lane], x0);
                    atomicAdd(&hacc[r][64 + lane], x1);
                }
            }
        }
        __syncthreads();   // scr reusable / hacc complete for this chunk
    }

    // writeout: natural-pair bf16 pack to h0 (matches mlp staging layout)
#pragma unroll
    for (int i = 0; i < 16; ++i) {
        int g = tid + 256 * i;
        int row = g >> 6, c = g & 63;
        int n = row0 + row;
        if (n < N_NODES) {
            unsigned int pk = (unsigned)f2bf(hacc[row][2 * c]) |
                              ((unsigned)f2bf(hacc[row][2 * c + 1]) << 16);
            h0[(size_t)n * 64 + c] = pk;
        }
    }
}

// ---------------------------------------------------------------------------
// MFMA helpers — B-fragments from frag-packed global WT (16B/lane coalesced)
// h has no __restrict__ — GEMM layers run IN PLACE on the wave's own
// 16-row band (per-wave in-order LDS; bands disjoint -> no hazard).
// ---------------------------------------------------------------------------
__device__ __forceinline__ void gemm_frags(const unsigned short* hIn,
                                           const unsigned short* __restrict__ WTl,
                                           floatx4 acc[8], int w, int lane)
{
    const int c = lane & 15, q = lane >> 4;
#pragma unroll
    for (int nt = 0; nt < 8; ++nt) acc[nt] = (floatx4){0.f, 0.f, 0.f, 0.f};
#pragma unroll
    for (int kt = 0; kt < 4; ++kt) {
        short8 a = *(const short8*)&hIn[(w * 16 + c) * WSTR + kt * 32 + q * 8];
#pragma unroll
        for (int nt = 0; nt < 8; ++nt) {
            short8 b = *(const short8*)&WTl[(nt * 256 + kt * 64 + lane) * 8];
            acc[nt] = __builtin_amdgcn_mfma_f32_16x16x32_bf16(a, b, acc[nt], 0, 0, 0);
        }
    }
}

// GEMM + bias + per-row LayerNorm + ReLU fused in registers, in-place in h.
__device__ __forceinline__ void gemm_layer_ln(unsigned short* h,
                                              const unsigned short* __restrict__ WTl,
                                              const float* __restrict__ bias,
                                              const float* __restrict__ g,
                                              const float* __restrict__ be,
                                              int w, int lane)
{
    const int c = lane & 15, q = lane >> 4;
    floatx4 acc[8];
    gemm_frags(h, WTl, acc, w, lane);

    float sum[4] = {0.f, 0.f, 0.f, 0.f};
    float sq[4]  = {0.f, 0.f, 0.f, 0.f};
#pragma unroll
    for (int nt = 0; nt < 8; ++nt) {
        float bv = bias[nt * 16 + c];
#pragma unroll
        for (int i = 0; i < 4; ++i) {
            float vv = acc[nt][i] + bv;
            acc[nt][i] = vv;
            sum[i] += vv; sq[i] += vv * vv;
        }
    }
#pragma unroll
    for (int m = 1; m < 16; m <<= 1) {
#pragma unroll
        for (int i = 0; i < 4; ++i) {
            sum[i] += __shfl_xor(sum[i], m);
            sq[i]  += __shfl_xor(sq[i], m);
        }
    }
    float mu[4], rstd[4];
#pragma unroll
    for (int i = 0; i < 4; ++i) {
        mu[i]   = sum[i] * (1.0f / 128.0f);
        rstd[i] = rsqrtf(sq[i] * (1.0f / 128.0f) - mu[i] * mu[i] + LN_EPS);
    }
#pragma unroll
    for (int nt = 0; nt < 8; ++nt) {
        float gw = g[nt * 16 + c];
        float bw = be[nt * 16 + c];
#pragma unroll
        for (int i = 0; i < 4; ++i) {
            float val = fmaxf(0.f, (acc[nt][i] - mu[i]) * rstd[i] * gw + bw);
            h[(w * 16 + q * 4 + i) * WSTR + nt * 16 + c] = f2bf(val);
        }
    }
}

// ---------------------------------------------------------------------------
// MLP kernel: stage h0 tile (bf16, coalesced uint4) -> LDS, then
// 3x MFMA GEMM in place (LN fused) -> fp32 out + per-graph stats.
// launch_bounds(256,4): cap 128 unified regs — the r0-proven spill-free
// regime for this exact GEMM (demand ~100).
// ---------------------------------------------------------------------------
__global__ __launch_bounds__(256, 4) void mlp_kernel(
    const unsigned int* __restrict__ h0,
    const unsigned short* __restrict__ WT,
    const float* __restrict__ b1, const float* __restrict__ g1,
    const float* __restrict__ be1,
    const float* __restrict__ b2, const float* __restrict__ g2,
    const float* __restrict__ be2,
    const float* __restrict__ b3, const int* __restrict__ batch,
    float* __restrict__ out, float* __restrict__ gstat)
{
    __shared__ unsigned short hA[64 * WSTR];    // 17.4 KB
    __shared__ float prm[7 * 128];              // 3.6 KB
    __shared__ float s_gsum[G_NUM], s_gsq[G_NUM], s_gcnt[G_NUM];

    const int tid = threadIdx.x;
    const int w = tid >> 6, lane = tid & 63;
    const int row0 = blockIdx.x * 64;

    if (tid < G_NUM) { s_gsum[tid] = 0.f; s_gsq[tid] = 0.f; s_gcnt[tid] = 0.f; }
    {
        const float* srcs[7] = {b1, g1, be1, b2, g2, be2, b3};
#pragma unroll
        for (int t = 0; t < 4; ++t) {
            int i = tid + t * 256;
            if (i < 7 * 128) prm[i] = srcs[i >> 7][i & 127];
        }
    }

    // ---- stage h0 tile -> hA (WSTR layout). 4 threads/row x 16 uints each.
    {
        const int r = tid >> 2;          // 0..63
        const int q4 = tid & 3;          // 4 chunks of 16 uints (64B)
        uint4* d = (uint4*)(((unsigned int*)hA) + r * (WSTR / 2) + q4 * 16);
        const int row = row0 + r;
        if (row < N_NODES) {
            const uint4* s = (const uint4*)&h0[(size_t)row * 64 + q4 * 16];
#pragma unroll
            for (int k = 0; k < 4; ++k) d[k] = s[k];
        } else {
            uint4 z = make_uint4(0, 0, 0, 0);
#pragma unroll
            for (int k = 0; k < 4; ++k) d[k] = z;
        }
    }
    __syncthreads();

    gemm_layer_ln(hA, WT,         &prm[0],   &prm[128], &prm[256], w, lane);
    gemm_layer_ln(hA, WT + 16384, &prm[384], &prm[512], &prm[640], w, lane);

    // layer 3 -> global + stats
    {
        const int c = lane & 15, q = lane >> 4;
        floatx4 acc3[8];
        gemm_frags(hA, WT + 32768, acc3, w, lane);
        float sum[4] = {0.f, 0.f, 0.f, 0.f};
        float sq[4]  = {0.f, 0.f, 0.f, 0.f};
#pragma unroll
        for (int nt = 0; nt < 8; ++nt) {
            float bv = prm[768 + nt * 16 + c];
#pragma unroll
            for (int i = 0; i < 4; ++i) {
                float vv = acc3[nt][i] + bv;
                size_t nrow = (size_t)row0 + w * 16 + q * 4 + i;
                if (nrow < N_NODES)
                    out[nrow * H + nt * 16 + c] = vv;
                sum[i] += vv; sq[i] += vv * vv;
            }
        }
#pragma unroll
        for (int m = 1; m < 16; m <<= 1) {
#pragma unroll
            for (int i = 0; i < 4; ++i) {
                sum[i] += __shfl_xor(sum[i], m);
                sq[i]  += __shfl_xor(sq[i], m);
            }
        }
        if (c == 0) {
#pragma unroll
            for (int i = 0; i < 4; ++i) {
                size_t nrow = (size_t)row0 + w * 16 + q * 4 + i;
                if (nrow < N_NODES) {
                    int g = batch[nrow];
                    atomicAdd(&s_gsum[g], sum[i]);
                    atomicAdd(&s_gsq[g], sq[i]);
                    atomicAdd(&s_gcnt[g], 1.0f);
                }
            }
        }
    }
    __syncthreads();
    if (tid < G_NUM && s_gcnt[tid] > 0.f) {
        unsafeAtomicAdd(&gstat[tid], s_gsum[tid]);
        unsafeAtomicAdd(&gstat[G_NUM + tid], s_gsq[tid]);
        unsafeAtomicAdd(&gstat[2 * G_NUM + tid], s_gcnt[tid]);
    }
}

// ---------------------------------------------------------------------------
// Graph-LN apply + ReLU (finalize folded in)
// ---------------------------------------------------------------------------
__global__ __launch_bounds__(256) void final_ln_kernel(
    float* __restrict__ h3, const int* __restrict__ batch,
    const float* __restrict__ lnw, const float* __restrict__ lnb,
    const float* __restrict__ gstat)
{
    int idx4 = blockIdx.x * 256 + threadIdx.x;
    if (idx4 >= N_NODES * 32) return;
    int node = idx4 >> 5;
    int c4 = (idx4 & 31) * 4;
    int g = batch[node];
    float s   = gstat[g];
    float qq  = gstat[G_NUM + g];
    float cnt = gstat[2 * G_NUM + g];
    float norm = fmaxf(cnt * (float)H, 1.0f);
    float mean = s / norm;
    float var  = qq / norm - mean * mean;
    float inv  = rsqrtf(var + LN_EPS);
    float4 v = ((const float4*)h3)[idx4];
    float4 w = *(const float4*)&lnw[c4];
    float4 b = *(const float4*)&lnb[c4];
    v.x = fmaxf(0.f, (v.x - mean) * inv * w.x + b.x);
    v.y = fmaxf(0.f, (v.y - mean) * inv * w.y + b.y);
    v.z = fmaxf(0.f, (v.z - mean) * inv * w.z + b.z);
    v.w = fmaxf(0.f, (v.w - mean) * inv * w.w + b.w);
    ((float4*)h3)[idx4] = v;
}

// ---------------------------------------------------------------------------
extern "C" void kernel_launch(void* const* d_in, const int* in_sizes, int n_in,
                              void* d_out, int out_size, void* d_ws, size_t ws_size,
                              hipStream_t stream)
{
    const float* node  = (const float*)d_in[0];
    const int*   ei    = (const int*)d_in[1];
    // d_in[2] = edge_attr (unused)
    const int*   batch = (const int*)d_in[3];
    const float* epsp  = (const float*)d_in[4];
    const float* W1    = (const float*)d_in[5];
    const float* b1    = (const float*)d_in[6];
    const float* g1    = (const float*)d_in[7];
    const float* be1   = (const float*)d_in[8];
    const float* W2    = (const float*)d_in[9];
    const float* b2    = (const float*)d_in[10];
    const float* g2    = (const float*)d_in[11];
    const float* be2   = (const float*)d_in[12];
    const float* W3    = (const float*)d_in[13];
    const float* b3    = (const float*)d_in[14];
    const float* lnw   = (const float*)d_in[15];
    const float* lnb   = (const float*)d_in[16];

    float* out = (float*)d_out;

    int* base = (int*)d_ws;
    float* gstat  = (float*)d_ws;
    int*   deg    = base + 512;
    int*   off    = deg + N_NODES;
    int*   cursor = off + N_NODES + 1;
    int*   csr    = cursor + N_NODES;
    int*   blksum = csr + N_EDGES;
    unsigned short* WT = (unsigned short*)(base + WT_IOFF);      // 16B-aligned

    // h0 placement: with room for a bf16 node table, nbf at NBF_IOFF and h0
    // after it; otherwise h0 takes the NBF slot and the gather reads fp32 node.
    const bool use_bf = (ws_size >= NEEDED_BF);
    unsigned int* nbf = (unsigned int*)(base + NBF_IOFF);
    unsigned int* h0  = use_bf ? (unsigned int*)(base + H0_BF_IOFF)
                               : (unsigned int*)(base + NBF_IOFF);

    // single memset covers gstat (512 floats) + adjacent deg (N ints)
    hipMemsetAsync(d_ws, 0, (512 + N_NODES) * sizeof(int), stream);

    hist_cvt_kernel<<<HIST_NB + (use_bf ? CVT_NB : 0), 256, 0, stream>>>(
        ei, deg, node, nbf);
    scan1_kernel<<<SCAN_NB, 256, 0, stream>>>(deg, off, blksum);
    scan23_kernel<<<(N_NODES + 255) / 256, 256, 0, stream>>>(off, blksum, cursor);
    fill_wt_kernel<<<FILL_NB + WT_NB, 256, 0, stream>>>(ei, cursor, csr,
                                                        W1, W2, W3, WT);

    if (use_bf)
        gather_kernel<true><<<NTILES, 256, 0, stream>>>(node, nbf, off, csr,
                                                        epsp, h0);
    else
        gather_kernel<false><<<NTILES, 256, 0, stream>>>(node, nbf, off, csr,
                                                         epsp, h0);

    mlp_kernel<<<NTILES, 256, 0, stream>>>(h0, WT, b1, g1, be1, b2, g2, be2,
                                           b3, batch, out, gstat);

    final_ln_kernel<<<(N_NODES * 32 + 255) / 256, 256, 0, stream>>>(
        out, batch, lnw, lnb, gstat);
}

// Round 7
// 698.285 us; speedup vs baseline: 1.0005x; 1.0005x over previous
//
#include <hip/hip_runtime.h>

#define N_NODES 100000
#define N_EDGES 600000
#define H 128
#define G_NUM 64
#define LN_EPS 1e-5f

// LDS bf16 row stride (conflict-free b128 frag reads)
#define WSTR 136

#define NTILES ((N_NODES + 63) / 64)     // 1563

#define SCAN_CHUNK 1024
#define SCAN_NB ((N_NODES + SCAN_CHUNK - 1) / SCAN_CHUNK)   // 98
#define HIST_NB ((N_EDGES + 255) / 256)                      // 2344
#define CVT_NB ((N_NODES * H / 8 + 255) / 256)               // 6250
#define FILL_NB ((N_EDGES + 255) / 256)                      // 2344
#define WT_NB ((3 * 16384 + 255) / 256)                      // 192

// edges per LDS chunk in gather; block edge count ~ Binom(E,64/N): mean 384,
// sd ~20 -> 1536 is mean+57sd; chunk loop is the correctness fallback anyway.
#define EBUF 1536

// ws layout (ints): gstat 512 | deg N | off N+1 | cursor N | csr E |
//                   blksum | WT (3*16k bf16) | [nbf (N*H bf16)] | h0 (N*H bf16)
#define WT_IOFF   900612
#define NBF_IOFF  925192                     // 16B-aligned
#define H0_BF_IOFF (NBF_IOFF + N_NODES * (H / 2))   // h0 after nbf (bf path)
#define NEEDED_BF  ((size_t)(H0_BF_IOFF + N_NODES * (H / 2)) * 4)     // ~54.9MB

typedef __attribute__((ext_vector_type(8))) short short8;
typedef __attribute__((ext_vector_type(4))) float floatx4;

__device__ __forceinline__ unsigned short f2bf(float x) {   // RNE fp32->bf16
    unsigned int u = __float_as_uint(x);
    u += 0x7fffu + ((u >> 16) & 1u);
    return (unsigned short)(u >> 16);
}

// Native LDS float add, fire-and-forget. HIP's atomicAdd on LDS float lowered
// to a CAS/flat path (r6: 461us at 2.2% VALUBusy, all waves stalled); the
// ds_add_f32 instruction is atomic at the bank, needs no return and no wait
// in the loop — the pre-barrier waitcnt drains it. addr = 32-bit LDS byte
// offset (low 32 bits of a shared generic pointer — HK addressing idiom).
__device__ __forceinline__ void lds_fadd(unsigned byte_off, float v) {
    asm volatile("ds_add_f32 %0, %1" :: "v"(byte_off), "v"(v) : "memory");
}
__device__ __forceinline__ void lds_fadd_o256(unsigned byte_off, float v) {
    asm volatile("ds_add_f32 %0, %1 offset:256" :: "v"(byte_off), "v"(v) : "memory");
}

// ---------------------------------------------------------------------------
// CSR hist + bf16 node staging in SPLIT-PAIR layout:
//   nbf[n*64 + c] = bf16(x[n][c]) | bf16(x[n][c+64])<<16   (c in [0,64))
// so the gather's lane-c dword feeds LDS adds at banks c and c+64 (2-way, free).
// ---------------------------------------------------------------------------
__global__ __launch_bounds__(256) void hist_cvt_kernel(
    const int* __restrict__ ei, int* __restrict__ deg,
    const float* __restrict__ node, unsigned int* __restrict__ node_bf)
{
    int gb = blockIdx.x;
    if (gb < HIST_NB) {
        int e = gb * 256 + threadIdx.x;
        if (e >= N_EDGES) return;
        atomicAdd(&deg[ei[N_EDGES + e]], 1);
    } else {
        int i = (gb - HIST_NB) * 256 + threadIdx.x;   // uint4 index, N*16 total
        if (i >= N_NODES * 16) return;
        int n = i >> 4;
        int c0 = (i & 15) * 4;
        const float4 a = *(const float4*)&node[(size_t)n * H + c0];
        const float4 b = *(const float4*)&node[(size_t)n * H + 64 + c0];
        uint4 p;
        p.x = (unsigned)f2bf(a.x) | ((unsigned)f2bf(b.x) << 16);
        p.y = (unsigned)f2bf(a.y) | ((unsigned)f2bf(b.y) << 16);
        p.z = (unsigned)f2bf(a.z) | ((unsigned)f2bf(b.z) << 16);
        p.w = (unsigned)f2bf(a.w) | ((unsigned)f2bf(b.w) << 16);
        ((uint4*)node_bf)[i] = p;
    }
}

__global__ __launch_bounds__(256) void scan1_kernel(
    const int* __restrict__ deg, int* __restrict__ off,
    int* __restrict__ blksum)
{
    __shared__ int sA[256], sB[256];
    const int tid = threadIdx.x;
    const int base = blockIdx.x * SCAN_CHUNK + tid * 4;
    int v[4];
#pragma unroll
    for (int j = 0; j < 4; ++j) {
        int i = base + j;
        v[j] = (i < N_NODES) ? deg[i] : 0;
    }
    int tsum = v[0] + v[1] + v[2] + v[3];
    int* a = sA; int* b = sB;
    a[tid] = tsum;
    __syncthreads();
#pragma unroll
    for (int o = 1; o < 256; o <<= 1) {
        int t = a[tid] + ((tid >= o) ? a[tid - o] : 0);
        b[tid] = t;
        __syncthreads();
        int* tmp = a; a = b; b = tmp;
    }
    int run = a[tid] - tsum;
#pragma unroll
    for (int j = 0; j < 4; ++j) {
        int i = base + j;
        if (i < N_NODES) off[i] = run;
        run += v[j];
    }
    if (tid == 255) blksum[blockIdx.x] = a[255];
}

__global__ __launch_bounds__(256) void scan23_kernel(
    int* __restrict__ off, const int* __restrict__ blksum,
    int* __restrict__ cursor)
{
    __shared__ int sA[128], sB[128];
    const int tid = threadIdx.x;
    if (tid < 128) sA[tid] = (tid < SCAN_NB) ? blksum[tid] : 0;
    __syncthreads();
    int* a = sA; int* b = sB;
#pragma unroll
    for (int o = 1; o < 128; o <<= 1) {
        int t = 0;
        if (tid < 128) t = a[tid] + ((tid >= o) ? a[tid - o] : 0);
        __syncthreads();
        if (tid < 128) b[tid] = t;
        __syncthreads();
        int* tmp = a; a = b; b = tmp;
    }
    int excl = 0;
    if (tid < 128) excl = a[tid] - ((tid < SCAN_NB) ? blksum[tid] : 0);
    __syncthreads();
    if (tid < 128) sA[tid] = excl;
    __syncthreads();

    int i = blockIdx.x * 256 + tid;
    if (i < N_NODES) {
        int val = off[i] + sA[i >> 10];
        off[i] = val;
        cursor[i] = val;
    }
    if (i == 0) off[N_NODES] = N_EDGES;
}

// fill + FRAGMENT-PACKED bf16 weights (r11 layout), one dispatch.
__global__ __launch_bounds__(256) void fill_wt_kernel(
    const int* __restrict__ ei, int* __restrict__ cursor,
    int* __restrict__ csr,
    const float* __restrict__ W1, const float* __restrict__ W2,
    const float* __restrict__ W3, unsigned short* __restrict__ WT)
{
    int gb = blockIdx.x;
    if (gb < FILL_NB) {
        int e = gb * 256 + threadIdx.x;
        if (e >= N_EDGES) return;
        int dst = ei[N_EDGES + e];
        int pos = atomicAdd(&cursor[dst], 1);
        csr[pos] = ei[e];
    } else {
        int idx = (gb - FILL_NB) * 256 + threadIdx.x;
        if (idx >= 3 * 16384) return;
        int l = idx >> 14, r = idx & 16383;
        int frag = r >> 3, j = r & 7;
        int lane = frag & 63, ktnt = frag >> 6;
        int kt = ktnt & 3, nt = ktnt >> 2;
        int c = lane & 15, q = lane >> 4;
        int n = nt * 16 + c;
        int k = kt * 32 + q * 8 + j;
        const float* W = (l == 0) ? W1 : ((l == 1) ? W2 : W3);
        WT[l * 16384 + r] = f2bf(W[k * 128 + n]);
    }
}

// ---------------------------------------------------------------------------
// GATHER v2.1 — edge-parallel LDS accumulation with NATIVE ds_add_f32.
// Block = 64 rows. hacc[64][128] f32 in LDS; all 4 waves stream the block's
// csr edges in batches of 8: uniform ds_read of packed (row<<18)|src ->
// 8 independent coalesced 256B row loads -> 16 ds_add_f32 fire-and-forget
// (banks 2-way=free via split-pair layout). ~10 inst/edge, no divergence,
// no waits in the add path.
// ---------------------------------------------------------------------------
template <bool NBF>
__global__ __launch_bounds__(256) void gather_kernel(
    const float* __restrict__ node, const unsigned int* __restrict__ nbf,
    const int* __restrict__ off, const int* __restrict__ csr,
    const float* __restrict__ epsp, unsigned int* __restrict__ h0)
{
    __shared__ float hacc[64][H];      // 32 KB
    __shared__ int   scr[EBUF];        // 6 KB
    __shared__ int   s_off[65];
    // ~38.4 KB -> 4 blocks/CU (LDS-capped; hacc alone caps at 4)

    const int tid = threadIdx.x;
    const int w = tid >> 6, lane = tid & 63;
    const int row0 = blockIdx.x * 64;
    const float epsv = 1.0f + epsp[0];

    // 32-bit LDS byte offset of hacc base (HK shared-pointer idiom)
    const unsigned hbase = (unsigned)(unsigned long long)&hacc[0][0];

    if (tid < 65) {
        int r = row0 + tid;
        s_off[tid] = off[(r > N_NODES) ? N_NODES : r];
    }

    // init hacc = (1+eps) * own  (split-pair source)
#pragma unroll
    for (int i = 0; i < 16; ++i) {
        int g = tid + 256 * i;           // u32-slot: row=g>>6, c=g&63
        int row = g >> 6, c = g & 63;
        int n = row0 + row;
        float x0 = 0.f, x1 = 0.f;
        if (n < N_NODES) {
            if constexpr (NBF) {
                unsigned int u = nbf[(size_t)n * 64 + c];
                x0 = __uint_as_float(u << 16);
                x1 = __uint_as_float(u & 0xffff0000u);
            } else {
                x0 = node[(size_t)n * H + c];
                x1 = node[(size_t)n * H + 64 + c];
            }
        }
        hacc[row][c]      = epsv * x0;
        hacc[row][64 + c] = epsv * x1;
    }
    __syncthreads();

    const int e_begin = s_off[0];
    const int cnt = s_off[64] - e_begin;

    for (int cb = 0; cb < cnt; cb += EBUF) {
        const int cwin = (cnt - cb < EBUF) ? (cnt - cb) : EBUF;
        // (a) fill scr with src ids (coalesced)
        for (int k = tid; k < cwin; k += 256) scr[k] = csr[e_begin + cb + k];
        __syncthreads();
        // (b) OR dst-row bits; each scr element has exactly one writer
        {
            const int r = tid >> 2, q = tid & 3;
            int klo = s_off[r] - e_begin;     if (klo < cb) klo = cb;
            int khi = s_off[r + 1] - e_begin; if (khi > cb + cwin) khi = cb + cwin;
            for (int k = klo + q; k < khi; k += 4)
                scr[k - cb] |= (r << 18);
        }
        __syncthreads();
        // (c) edge processing, wave-strided batches of 8
        const int cend = cb + cwin;
        for (int base = cb + w * 8; base < cend; base += 32) {
            const int m = (cend - base < 8) ? (cend - base) : 8;
            if (m == 8) {
                int nbv[8], rv[8];
#pragma unroll
                for (int j = 0; j < 8; ++j) {
                    int pk = __builtin_amdgcn_readfirstlane(scr[base - cb + j]);
                    nbv[j] = pk & 0x3FFFF;
                    rv[j] = pk >> 18;
                }
                float vx[8], vy[8];
#pragma unroll
                for (int j = 0; j < 8; ++j) {
                    if constexpr (NBF) {
                        unsigned int u = nbf[(size_t)nbv[j] * 64 + lane];
                        vx[j] = __uint_as_float(u << 16);
                        vy[j] = __uint_as_float(u & 0xffff0000u);
                    } else {
                        vx[j] = node[(size_t)nbv[j] * H + lane];
                        vy[j] = node[(size_t)nbv[j] * H + 64 + lane];
                    }
                }
#pragma unroll
                for (int j = 0; j < 8; ++j) {
                    unsigned o = hbase + (((rv[j] << 7) + lane) << 2);
                    lds_fadd(o, vx[j]);          // hacc[r][lane]
                    lds_fadd_o256(o, vy[j]);     // hacc[r][64+lane]
                }
            } else {
                for (int j = 0; j < m; ++j) {
                    int pk = __builtin_amdgcn_readfirstlane(scr[base - cb + j]);
                    int nb = pk & 0x3FFFF;
                    int r  = pk >> 18;
                    float x0, x1;
                    if constexpr (NBF) {
                        unsigned int u = nbf[(size_t)nb * 64 + lane];
                        x0 = __uint_as_float(u << 16);
                        x1 = __uint_as_float(u & 0xffff0000u);
                    } else {
                        x0 = node[(size_t)nb * H + lane];
                        x1 = node[(size_t)nb * H + 64 + lane];
                    }
                    unsigned o = hbase + (((r << 7) + lane) << 2);
                    lds_fadd(o, x0);
                    lds_fadd_o256(o, x1);
                }
            }
        }
        __syncthreads();   // drains ds_adds; scr reusable; hacc complete
    }

    // writeout: natural-pair bf16 pack to h0 (matches mlp staging layout)
#pragma unroll
    for (int i = 0; i < 16; ++i) {
        int g = tid + 256 * i;
        int row = g >> 6, c = g & 63;
        int n = row0 + row;
        if (n < N_NODES) {
            unsigned int pk = (unsigned)f2bf(hacc[row][2 * c]) |
                              ((unsigned)f2bf(hacc[row][2 * c + 1]) << 16);
            h0[(size_t)n * 64 + c] = pk;
        }
    }
}

// ---------------------------------------------------------------------------
// MFMA helpers — B-fragments from frag-packed global WT (16B/lane coalesced)
// h has no __restrict__ — GEMM layers run IN PLACE on the wave's own
// 16-row band (per-wave in-order LDS; bands disjoint -> no hazard).
// ---------------------------------------------------------------------------
__device__ __forceinline__ void gemm_frags(const unsigned short* hIn,
                                           const unsigned short* __restrict__ WTl,
                                           floatx4 acc[8], int w, int lane)
{
    const int c = lane & 15, q = lane >> 4;
#pragma unroll
    for (int nt = 0; nt < 8; ++nt) acc[nt] = (floatx4){0.f, 0.f, 0.f, 0.f};
#pragma unroll
    for (int kt = 0; kt < 4; ++kt) {
        short8 a = *(const short8*)&hIn[(w * 16 + c) * WSTR + kt * 32 + q * 8];
#pragma unroll
        for (int nt = 0; nt < 8; ++nt) {
            short8 b = *(const short8*)&WTl[(nt * 256 + kt * 64 + lane) * 8];
            acc[nt] = __builtin_amdgcn_mfma_f32_16x16x32_bf16(a, b, acc[nt], 0, 0, 0);
        }
    }
}

// GEMM + bias + per-row LayerNorm + ReLU fused in registers, in-place in h.
__device__ __forceinline__ void gemm_layer_ln(unsigned short* h,
                                              const unsigned short* __restrict__ WTl,
                                              const float* __restrict__ bias,
                                              const float* __restrict__ g,
                                              const float* __restrict__ be,
                                              int w, int lane)
{
    const int c = lane & 15, q = lane >> 4;
    floatx4 acc[8];
    gemm_frags(h, WTl, acc, w, lane);

    float sum[4] = {0.f, 0.f, 0.f, 0.f};
    float sq[4]  = {0.f, 0.f, 0.f, 0.f};
#pragma unroll
    for (int nt = 0; nt < 8; ++nt) {
        float bv = bias[nt * 16 + c];
#pragma unroll
        for (int i = 0; i < 4; ++i) {
            float vv = acc[nt][i] + bv;
            acc[nt][i] = vv;
            sum[i] += vv; sq[i] += vv * vv;
        }
    }
#pragma unroll
    for (int m = 1; m < 16; m <<= 1) {
#pragma unroll
        for (int i = 0; i < 4; ++i) {
            sum[i] += __shfl_xor(sum[i], m);
            sq[i]  += __shfl_xor(sq[i], m);
        }
    }
    float mu[4], rstd[4];
#pragma unroll
    for (int i = 0; i < 4; ++i) {
        mu[i]   = sum[i] * (1.0f / 128.0f);
        rstd[i] = rsqrtf(sq[i] * (1.0f / 128.0f) - mu[i] * mu[i] + LN_EPS);
    }
#pragma unroll
    for (int nt = 0; nt < 8; ++nt) {
        float gw = g[nt * 16 + c];
        float bw = be[nt * 16 + c];
#pragma unroll
        for (int i = 0; i < 4; ++i) {
            float val = fmaxf(0.f, (acc[nt][i] - mu[i]) * rstd[i] * gw + bw);
            h[(w * 16 + q * 4 + i) * WSTR + nt * 16 + c] = f2bf(val);
        }
    }
}

// ---------------------------------------------------------------------------
// MLP kernel: stage h0 tile (bf16, coalesced uint4) -> LDS, then
// 3x MFMA GEMM in place (LN fused) -> fp32 out + per-graph stats.
// launch_bounds(256,4): cap 128 unified regs — the r0-proven spill-free
// regime for this exact GEMM (demand ~100).
// ---------------------------------------------------------------------------
__global__ __launch_bounds__(256, 4) void mlp_kernel(
    const unsigned int* __restrict__ h0,
    const unsigned short* __restrict__ WT,
    const float* __restrict__ b1, const float* __restrict__ g1,
    const float* __restrict__ be1,
    const float* __restrict__ b2, const float* __restrict__ g2,
    const float* __restrict__ be2,
    const float* __restrict__ b3, const int* __restrict__ batch,
    float* __restrict__ out, float* __restrict__ gstat)
{
    __shared__ unsigned short hA[64 * WSTR];    // 17.4 KB
    __shared__ float prm[7 * 128];              // 3.6 KB
    __shared__ float s_gsum[G_NUM], s_gsq[G_NUM], s_gcnt[G_NUM];

    const int tid = threadIdx.x;
    const int w = tid >> 6, lane = tid & 63;
    const int row0 = blockIdx.x * 64;

    if (tid < G_NUM) { s_gsum[tid] = 0.f; s_gsq[tid] = 0.f; s_gcnt[tid] = 0.f; }
    {
        const float* srcs[7] = {b1, g1, be1, b2, g2, be2, b3};
#pragma unroll
        for (int t = 0; t < 4; ++t) {
            int i = tid + t * 256;
            if (i < 7 * 128) prm[i] = srcs[i >> 7][i & 127];
        }
    }

    // ---- stage h0 tile -> hA (WSTR layout). 4 threads/row x 16 uints each.
    {
        const int r = tid >> 2;          // 0..63
        const int q4 = tid & 3;          // 4 chunks of 16 uints (64B)
        uint4* d = (uint4*)(((unsigned int*)hA) + r * (WSTR / 2) + q4 * 16);
        const int row = row0 + r;
        if (row < N_NODES) {
            const uint4* s = (const uint4*)&h0[(size_t)row * 64 + q4 * 16];
#pragma unroll
            for (int k = 0; k < 4; ++k) d[k] = s[k];
        } else {
            uint4 z = make_uint4(0, 0, 0, 0);
#pragma unroll
            for (int k = 0; k < 4; ++k) d[k] = z;
        }
    }
    __syncthreads();

    gemm_layer_ln(hA, WT,         &prm[0],   &prm[128], &prm[256], w, lane);
    gemm_layer_ln(hA, WT + 16384, &prm[384], &prm[512], &prm[640], w, lane);

    // layer 3 -> global + stats
    {
        const int c = lane & 15, q = lane >> 4;
        floatx4 acc3[8];
        gemm_frags(hA, WT + 32768, acc3, w, lane);
        float sum[4] = {0.f, 0.f, 0.f, 0.f};
        float sq[4]  = {0.f, 0.f, 0.f, 0.f};
#pragma unroll
        for (int nt = 0; nt < 8; ++nt) {
            float bv = prm[768 + nt * 16 + c];
#pragma unroll
            for (int i = 0; i < 4; ++i) {
                float vv = acc3[nt][i] + bv;
                size_t nrow = (size_t)row0 + w * 16 + q * 4 + i;
                if (nrow < N_NODES)
                    out[nrow * H + nt * 16 + c] = vv;
                sum[i] += vv; sq[i] += vv * vv;
            }
        }
#pragma unroll
        for (int m = 1; m < 16; m <<= 1) {
#pragma unroll
            for (int i = 0; i < 4; ++i) {
                sum[i] += __shfl_xor(sum[i], m);
                sq[i]  += __shfl_xor(sq[i], m);
            }
        }
        if (c == 0) {
#pragma unroll
            for (int i = 0; i < 4; ++i) {
                size_t nrow = (size_t)row0 + w * 16 + q * 4 + i;
                if (nrow < N_NODES) {
                    int g = batch[nrow];
                    atomicAdd(&s_gsum[g], sum[i]);
                    atomicAdd(&s_gsq[g], sq[i]);
                    atomicAdd(&s_gcnt[g], 1.0f);
                }
            }
        }
    }
    __syncthreads();
    if (tid < G_NUM && s_gcnt[tid] > 0.f) {
        unsafeAtomicAdd(&gstat[tid], s_gsum[tid]);
        unsafeAtomicAdd(&gstat[G_NUM + tid], s_gsq[tid]);
        unsafeAtomicAdd(&gstat[2 * G_NUM + tid], s_gcnt[tid]);
    }
}

// ---------------------------------------------------------------------------
// Graph-LN apply + ReLU (finalize folded in)
// ---------------------------------------------------------------------------
__global__ __launch_bounds__(256) void final_ln_kernel(
    float* __restrict__ h3, const int* __restrict__ batch,
    const float* __restrict__ lnw, const float* __restrict__ lnb,
    const float* __restrict__ gstat)
{
    int idx4 = blockIdx.x * 256 + threadIdx.x;
    if (idx4 >= N_NODES * 32) return;
    int node = idx4 >> 5;
    int c4 = (idx4 & 31) * 4;
    int g = batch[node];
    float s   = gstat[g];
    float qq  = gstat[G_NUM + g];
    float cnt = gstat[2 * G_NUM + g];
    float norm = fmaxf(cnt * (float)H, 1.0f);
    float mean = s / norm;
    float var  = qq / norm - mean * mean;
    float inv  = rsqrtf(var + LN_EPS);
    float4 v = ((const float4*)h3)[idx4];
    float4 w = *(const float4*)&lnw[c4];
    float4 b = *(const float4*)&lnb[c4];
    v.x = fmaxf(0.f, (v.x - mean) * inv * w.x + b.x);
    v.y = fmaxf(0.f, (v.y - mean) * inv * w.y + b.y);
    v.z = fmaxf(0.f, (v.z - mean) * inv * w.z + b.z);
    v.w = fmaxf(0.f, (v.w - mean) * inv * w.w + b.w);
    ((float4*)h3)[idx4] = v;
}

// ---------------------------------------------------------------------------
extern "C" void kernel_launch(void* const* d_in, const int* in_sizes, int n_in,
                              void* d_out, int out_size, void* d_ws, size_t ws_size,
                              hipStream_t stream)
{
    const float* node  = (const float*)d_in[0];
    const int*   ei    = (const int*)d_in[1];
    // d_in[2] = edge_attr (unused)
    const int*   batch = (const int*)d_in[3];
    const float* epsp  = (const float*)d_in[4];
    const float* W1    = (const float*)d_in[5];
    const float* b1    = (const float*)d_in[6];
    const float* g1    = (const float*)d_in[7];
    const float* be1   = (const float*)d_in[8];
    const float* W2    = (const float*)d_in[9];
    const float* b2    = (const float*)d_in[10];
    const float* g2    = (const float*)d_in[11];
    const float* be2   = (const float*)d_in[12];
    const float* W3    = (const float*)d_in[13];
    const float* b3    = (const float*)d_in[14];
    const float* lnw   = (const float*)d_in[15];
    const float* lnb   = (const float*)d_in[16];

    float* out = (float*)d_out;

    int* base = (int*)d_ws;
    float* gstat  = (float*)d_ws;
    int*   deg    = base + 512;
    int*   off    = deg + N_NODES;
    int*   cursor = off + N_NODES + 1;
    int*   csr    = cursor + N_NODES;
    int*   blksum = csr + N_EDGES;
    unsigned short* WT = (unsigned short*)(base + WT_IOFF);      // 16B-aligned

    // h0 placement: with room for a bf16 node table, nbf at NBF_IOFF and h0
    // after it; otherwise h0 takes the NBF slot and the gather reads fp32 node.
    const bool use_bf = (ws_size >= NEEDED_BF);
    unsigned int* nbf = (unsigned int*)(base + NBF_IOFF);
    unsigned int* h0  = use_bf ? (unsigned int*)(base + H0_BF_IOFF)
                               : (unsigned int*)(base + NBF_IOFF);

    // single memset covers gstat (512 floats) + adjacent deg (N ints)
    hipMemsetAsync(d_ws, 0, (512 + N_NODES) * sizeof(int), stream);

    hist_cvt_kernel<<<HIST_NB + (use_bf ? CVT_NB : 0), 256, 0, stream>>>(
        ei, deg, node, nbf);
    scan1_kernel<<<SCAN_NB, 256, 0, stream>>>(deg, off, blksum);
    scan23_kernel<<<(N_NODES + 255) / 256, 256, 0, stream>>>(off, blksum, cursor);
    fill_wt_kernel<<<FILL_NB + WT_NB, 256, 0, stream>>>(ei, cursor, csr,
                                                        W1, W2, W3, WT);

    if (use_bf)
        gather_kernel<true><<<NTILES, 256, 0, stream>>>(node, nbf, off, csr,
                                                        epsp, h0);
    else
        gather_kernel<false><<<NTILES, 256, 0, stream>>>(node, nbf, off, csr,
                                                         epsp, h0);

    mlp_kernel<<<NTILES, 256, 0, stream>>>(h0, WT, b1, g1, be1, b2, g2, be2,
                                           b3, batch, out, gstat);

    final_ln_kernel<<<(N_NODES * 32 + 255) / 256, 256, 0, stream>>>(
        out, batch, lnw, lnb, gstat);
}

// Round 8
// 304.146 us; speedup vs baseline: 2.2971x; 2.2959x over previous
//
#include <hip/hip_runtime.h>

#define N_NODES 100000
#define N_EDGES 600000
#define H 128
#define G_NUM 64
#define LN_EPS 1e-5f

// LDS bf16 row stride (conflict-free b128 frag reads)
#define WSTR 136

#define NTILES ((N_NODES + 63) / 64)     // 1563

#define SCAN_CHUNK 1024
#define SCAN_NB ((N_NODES + SCAN_CHUNK - 1) / SCAN_CHUNK)   // 98
#define HIST_NB ((N_EDGES + 255) / 256)                      // 2344
#define CVT_NB ((N_NODES * H / 8 + 255) / 256)               // 6250
#define FILL_NB ((N_EDGES + 255) / 256)                      // 2344
#define WT_NB ((3 * 16384 + 255) / 256)                      // 192

// per-wave csr scratch; wave cnt ~ Binom(E,16/N): mean 96, sd ~10.
#define SCR_MAX 272

// ws layout (ints): gstat 512 | deg N | off N+1 | cursor N | csr E |
//                   blksum | WT (3*16k bf16) | [nbf (N*H bf16)] | h0 (N*H bf16)
#define WT_IOFF   900612
#define NBF_IOFF  925192                     // 16B-aligned
#define H0_BF_IOFF (NBF_IOFF + N_NODES * (H / 2))   // h0 after nbf (bf path)
#define NEEDED_BF  ((size_t)(H0_BF_IOFF + N_NODES * (H / 2)) * 4)     // ~54.9MB

typedef __attribute__((ext_vector_type(8))) short short8;
typedef __attribute__((ext_vector_type(4))) float floatx4;

__device__ __forceinline__ unsigned short f2bf(float x) {   // RNE fp32->bf16
    unsigned int u = __float_as_uint(x);
    u += 0x7fffu + ((u >> 16) & 1u);
    return (unsigned short)(u >> 16);
}

// ---------------------------------------------------------------------------
// CSR hist + bf16 node staging, NATURAL-PAIR layout (r2-r5 proven):
//   nbf[n*64 + c] = bf16(x[n][2c]) | bf16(x[n][2c+1])<<16
// ---------------------------------------------------------------------------
__global__ __launch_bounds__(256) void hist_cvt_kernel(
    const int* __restrict__ ei, int* __restrict__ deg,
    const float* __restrict__ node, unsigned int* __restrict__ node_bf)
{
    int gb = blockIdx.x;
    if (gb < HIST_NB) {
        int e = gb * 256 + threadIdx.x;
        if (e >= N_EDGES) return;
        atomicAdd(&deg[ei[N_EDGES + e]], 1);
    } else {
        int i = (gb - HIST_NB) * 256 + threadIdx.x;   // 8-float group index
        if (i >= N_NODES * H / 8) return;
        float4 a = ((const float4*)node)[i * 2];
        float4 b = ((const float4*)node)[i * 2 + 1];
        uint4 p;
        p.x = (unsigned)f2bf(a.x) | ((unsigned)f2bf(a.y) << 16);
        p.y = (unsigned)f2bf(a.z) | ((unsigned)f2bf(a.w) << 16);
        p.z = (unsigned)f2bf(b.x) | ((unsigned)f2bf(b.y) << 16);
        p.w = (unsigned)f2bf(b.z) | ((unsigned)f2bf(b.w) << 16);
        ((uint4*)node_bf)[i] = p;
    }
}

__global__ __launch_bounds__(256) void scan1_kernel(
    const int* __restrict__ deg, int* __restrict__ off,
    int* __restrict__ blksum)
{
    __shared__ int sA[256], sB[256];
    const int tid = threadIdx.x;
    const int base = blockIdx.x * SCAN_CHUNK + tid * 4;
    int v[4];
#pragma unroll
    for (int j = 0; j < 4; ++j) {
        int i = base + j;
        v[j] = (i < N_NODES) ? deg[i] : 0;
    }
    int tsum = v[0] + v[1] + v[2] + v[3];
    int* a = sA; int* b = sB;
    a[tid] = tsum;
    __syncthreads();
#pragma unroll
    for (int o = 1; o < 256; o <<= 1) {
        int t = a[tid] + ((tid >= o) ? a[tid - o] : 0);
        b[tid] = t;
        __syncthreads();
        int* tmp = a; a = b; b = tmp;
    }
    int run = a[tid] - tsum;
#pragma unroll
    for (int j = 0; j < 4; ++j) {
        int i = base + j;
        if (i < N_NODES) off[i] = run;
        run += v[j];
    }
    if (tid == 255) blksum[blockIdx.x] = a[255];
}

__global__ __launch_bounds__(256) void scan23_kernel(
    int* __restrict__ off, const int* __restrict__ blksum,
    int* __restrict__ cursor)
{
    __shared__ int sA[128], sB[128];
    const int tid = threadIdx.x;
    if (tid < 128) sA[tid] = (tid < SCAN_NB) ? blksum[tid] : 0;
    __syncthreads();
    int* a = sA; int* b = sB;
#pragma unroll
    for (int o = 1; o < 128; o <<= 1) {
        int t = 0;
        if (tid < 128) t = a[tid] + ((tid >= o) ? a[tid - o] : 0);
        __syncthreads();
        if (tid < 128) b[tid] = t;
        __syncthreads();
        int* tmp = a; a = b; b = tmp;
    }
    int excl = 0;
    if (tid < 128) excl = a[tid] - ((tid < SCAN_NB) ? blksum[tid] : 0);
    __syncthreads();
    if (tid < 128) sA[tid] = excl;
    __syncthreads();

    int i = blockIdx.x * 256 + tid;
    if (i < N_NODES) {
        int val = off[i] + sA[i >> 10];
        off[i] = val;
        cursor[i] = val;
    }
    if (i == 0) off[N_NODES] = N_EDGES;
}

// fill + FRAGMENT-PACKED bf16 weights (r11 layout), one dispatch.
__global__ __launch_bounds__(256) void fill_wt_kernel(
    const int* __restrict__ ei, int* __restrict__ cursor,
    int* __restrict__ csr,
    const float* __restrict__ W1, const float* __restrict__ W2,
    const float* __restrict__ W3, unsigned short* __restrict__ WT)
{
    int gb = blockIdx.x;
    if (gb < FILL_NB) {
        int e = gb * 256 + threadIdx.x;
        if (e >= N_EDGES) return;
        int dst = ei[N_EDGES + e];
        int pos = atomicAdd(&cursor[dst], 1);
        csr[pos] = ei[e];
    } else {
        int idx = (gb - FILL_NB) * 256 + threadIdx.x;
        if (idx >= 3 * 16384) return;
        int l = idx >> 14, r = idx & 16383;
        int frag = r >> 3, j = r & 7;
        int lane = frag & 63, ktnt = frag >> 6;
        int kt = ktnt & 3, nt = ktnt >> 2;
        int c = lane & 15, q = lane >> 4;
        int n = nt * 16 + c;
        int k = kt * 32 + q * 8 + j;
        const float* W = (l == 0) ? W1 : ((l == 1) ? W2 : W3);
        WT[l * 16384 + r] = f2bf(W[k * 128 + n]);
    }
}

// ---------------------------------------------------------------------------
// GATHER v3 — row-serial, 8-deep batched register accumulation.
// (r5 chain-walk: 100us, VALU-limited at ~68 inst/edge — arithmetic closed:
//  68*600K/512 = 33us issue = measured 33% VALUBusy. r6/r7 edge-parallel
//  LDS-atomic: 460us with ALL pipes idle regardless of atomic lowering —
//  structure abandoned, ERRATA on the r6 CAS theory.)
// Wave = 16 rows. Per row: issue own + <=8 neighbor dword loads back-to-back
// (raw bf16-pair dwords, no unpack between loads), then unpack+add.
// All loop bounds wave-uniform -> no divergence; unrolled j -> compile-time
// array indices (no scratch). ~6-8 inst/edge, 8 loads in flight.
// ~45 VGPR, 4.4KB LDS -> 8 blocks/CU.
// ---------------------------------------------------------------------------
template <bool NBF>
__global__ __launch_bounds__(256) void gather_kernel(
    const float* __restrict__ node, const unsigned int* __restrict__ nbf,
    const int* __restrict__ off, const int* __restrict__ csr,
    const float* __restrict__ epsp, unsigned int* __restrict__ h0)
{
    __shared__ int scr4[4][SCR_MAX];
    const int tid = threadIdx.x;
    const int w = tid >> 6, lane = tid & 63;
    const int n0 = blockIdx.x * 64 + w * 16;
    const float epsv = 1.0f + epsp[0];

    const float2* np2 = (const float2*)node;

    int oidx = n0 + ((lane < 17) ? lane : 16);
    if (oidx > N_NODES) oidx = N_NODES;
    const int offl = off[oidx];
    const int e_begin = __shfl(offl, 0);
    const int e_end   = __shfl(offl, 16);
    const int cnt = e_end - e_begin;

    int* scr = scr4[w];
    const bool use_scr = (cnt <= SCR_MAX);
    if (use_scr) {
        for (int k = lane; k < cnt; k += 64) scr[k] = csr[e_begin + k];
        __threadfence_block();   // drain ds_writes before same-wave reads
    }

    for (int i = 0; i < 16; ++i) {
        int n = n0 + i;
        if (n >= N_NODES) break;             // wave-uniform
        const int kb = __shfl(offl, i) - e_begin;
        const int ke = __shfl(offl, i + 1) - e_begin;

        float a0, a1;
        if constexpr (NBF) {
            unsigned uo = nbf[(size_t)n * 64 + lane];
            a0 = epsv * __uint_as_float(uo << 16);
            a1 = epsv * __uint_as_float(uo & 0xffff0000u);
        } else {
            float2 own = np2[(size_t)n * 64 + lane];
            a0 = epsv * own.x;
            a1 = epsv * own.y;
        }

        for (int k = kb; k < ke; k += 8) {    // wave-uniform bounds
            const int m = ke - k;             // wave-uniform
            if constexpr (NBF) {
                unsigned uu[8];
#pragma unroll
                for (int j = 0; j < 8; ++j) {
                    if (j < m) {
                        int nb = __builtin_amdgcn_readfirstlane(
                            use_scr ? scr[k + j] : csr[e_begin + k + j]);
                        uu[j] = nbf[(size_t)nb * 64 + lane];
                    }
                }
#pragma unroll
                for (int j = 0; j < 8; ++j) {
                    if (j < m) {
                        a0 += __uint_as_float(uu[j] << 16);
                        a1 += __uint_as_float(uu[j] & 0xffff0000u);
                    }
                }
            } else {
                float2 vv[8];
#pragma unroll
                for (int j = 0; j < 8; ++j) {
                    if (j < m) {
                        int nb = __builtin_amdgcn_readfirstlane(
                            use_scr ? scr[k + j] : csr[e_begin + k + j]);
                        vv[j] = np2[(size_t)nb * 64 + lane];
                    }
                }
#pragma unroll
                for (int j = 0; j < 8; ++j) {
                    if (j < m) { a0 += vv[j].x; a1 += vv[j].y; }
                }
            }
        }

        unsigned pk = (unsigned)f2bf(a0) | ((unsigned)f2bf(a1) << 16);
        h0[(size_t)n * 64 + lane] = pk;
    }
}

// ---------------------------------------------------------------------------
// MFMA helpers — B-fragments from frag-packed global WT (16B/lane coalesced)
// h has no __restrict__ — GEMM layers run IN PLACE on the wave's own
// 16-row band (per-wave in-order LDS; bands disjoint -> no hazard).
// ---------------------------------------------------------------------------
__device__ __forceinline__ void gemm_frags(const unsigned short* hIn,
                                           const unsigned short* __restrict__ WTl,
                                           floatx4 acc[8], int w, int lane)
{
    const int c = lane & 15, q = lane >> 4;
#pragma unroll
    for (int nt = 0; nt < 8; ++nt) acc[nt] = (floatx4){0.f, 0.f, 0.f, 0.f};
#pragma unroll
    for (int kt = 0; kt < 4; ++kt) {
        short8 a = *(const short8*)&hIn[(w * 16 + c) * WSTR + kt * 32 + q * 8];
#pragma unroll
        for (int nt = 0; nt < 8; ++nt) {
            short8 b = *(const short8*)&WTl[(nt * 256 + kt * 64 + lane) * 8];
            acc[nt] = __builtin_amdgcn_mfma_f32_16x16x32_bf16(a, b, acc[nt], 0, 0, 0);
        }
    }
}

// GEMM + bias + per-row LayerNorm + ReLU fused in registers, in-place in h.
__device__ __forceinline__ void gemm_layer_ln(unsigned short* h,
                                              const unsigned short* __restrict__ WTl,
                                              const float* __restrict__ bias,
                                              const float* __restrict__ g,
                                              const float* __restrict__ be,
                                              int w, int lane)
{
    const int c = lane & 15, q = lane >> 4;
    floatx4 acc[8];
    gemm_frags(h, WTl, acc, w, lane);

    float sum[4] = {0.f, 0.f, 0.f, 0.f};
    float sq[4]  = {0.f, 0.f, 0.f, 0.f};
#pragma unroll
    for (int nt = 0; nt < 8; ++nt) {
        float bv = bias[nt * 16 + c];
#pragma unroll
        for (int i = 0; i < 4; ++i) {
            float vv = acc[nt][i] + bv;
            acc[nt][i] = vv;
            sum[i] += vv; sq[i] += vv * vv;
        }
    }
#pragma unroll
    for (int m = 1; m < 16; m <<= 1) {
#pragma unroll
        for (int i = 0; i < 4; ++i) {
            sum[i] += __shfl_xor(sum[i], m);
            sq[i]  += __shfl_xor(sq[i], m);
        }
    }
    float mu[4], rstd[4];
#pragma unroll
    for (int i = 0; i < 4; ++i) {
        mu[i]   = sum[i] * (1.0f / 128.0f);
        rstd[i] = rsqrtf(sq[i] * (1.0f / 128.0f) - mu[i] * mu[i] + LN_EPS);
    }
#pragma unroll
    for (int nt = 0; nt < 8; ++nt) {
        float gw = g[nt * 16 + c];
        float bw = be[nt * 16 + c];
#pragma unroll
        for (int i = 0; i < 4; ++i) {
            float val = fmaxf(0.f, (acc[nt][i] - mu[i]) * rstd[i] * gw + bw);
            h[(w * 16 + q * 4 + i) * WSTR + nt * 16 + c] = f2bf(val);
        }
    }
}

// ---------------------------------------------------------------------------
// MLP kernel: stage h0 tile (bf16, coalesced uint4) -> LDS, then
// 3x MFMA GEMM in place (LN fused) -> fp32 out + per-graph stats.
// launch_bounds(256,4): cap 128 unified regs — the r0-proven spill-free
// regime for this exact GEMM (demand ~100).
// ---------------------------------------------------------------------------
__global__ __launch_bounds__(256, 4) void mlp_kernel(
    const unsigned int* __restrict__ h0,
    const unsigned short* __restrict__ WT,
    const float* __restrict__ b1, const float* __restrict__ g1,
    const float* __restrict__ be1,
    const float* __restrict__ b2, const float* __restrict__ g2,
    const float* __restrict__ be2,
    const float* __restrict__ b3, const int* __restrict__ batch,
    float* __restrict__ out, float* __restrict__ gstat)
{
    __shared__ unsigned short hA[64 * WSTR];    // 17.4 KB
    __shared__ float prm[7 * 128];              // 3.6 KB
    __shared__ float s_gsum[G_NUM], s_gsq[G_NUM], s_gcnt[G_NUM];

    const int tid = threadIdx.x;
    const int w = tid >> 6, lane = tid & 63;
    const int row0 = blockIdx.x * 64;

    if (tid < G_NUM) { s_gsum[tid] = 0.f; s_gsq[tid] = 0.f; s_gcnt[tid] = 0.f; }
    {
        const float* srcs[7] = {b1, g1, be1, b2, g2, be2, b3};
#pragma unroll
        for (int t = 0; t < 4; ++t) {
            int i = tid + t * 256;
            if (i < 7 * 128) prm[i] = srcs[i >> 7][i & 127];
        }
    }

    // ---- stage h0 tile -> hA (WSTR layout). 4 threads/row x 16 uints each.
    {
        const int r = tid >> 2;          // 0..63
        const int q4 = tid & 3;          // 4 chunks of 16 uints (64B)
        uint4* d = (uint4*)(((unsigned int*)hA) + r * (WSTR / 2) + q4 * 16);
        const int row = row0 + r;
        if (row < N_NODES) {
            const uint4* s = (const uint4*)&h0[(size_t)row * 64 + q4 * 16];
#pragma unroll
            for (int k = 0; k < 4; ++k) d[k] = s[k];
        } else {
            uint4 z = make_uint4(0, 0, 0, 0);
#pragma unroll
            for (int k = 0; k < 4; ++k) d[k] = z;
        }
    }
    __syncthreads();

    gemm_layer_ln(hA, WT,         &prm[0],   &prm[128], &prm[256], w, lane);
    gemm_layer_ln(hA, WT + 16384, &prm[384], &prm[512], &prm[640], w, lane);

    // layer 3 -> global + stats
    {
        const int c = lane & 15, q = lane >> 4;
        floatx4 acc3[8];
        gemm_frags(hA, WT + 32768, acc3, w, lane);
        float sum[4] = {0.f, 0.f, 0.f, 0.f};
        float sq[4]  = {0.f, 0.f, 0.f, 0.f};
#pragma unroll
        for (int nt = 0; nt < 8; ++nt) {
            float bv = prm[768 + nt * 16 + c];
#pragma unroll
            for (int i = 0; i < 4; ++i) {
                float vv = acc3[nt][i] + bv;
                size_t nrow = (size_t)row0 + w * 16 + q * 4 + i;
                if (nrow < N_NODES)
                    out[nrow * H + nt * 16 + c] = vv;
                sum[i] += vv; sq[i] += vv * vv;
            }
        }
#pragma unroll
        for (int m = 1; m < 16; m <<= 1) {
#pragma unroll
            for (int i = 0; i < 4; ++i) {
                sum[i] += __shfl_xor(sum[i], m);
                sq[i]  += __shfl_xor(sq[i], m);
            }
        }
        if (c == 0) {
#pragma unroll
            for (int i = 0; i < 4; ++i) {
                size_t nrow = (size_t)row0 + w * 16 + q * 4 + i;
                if (nrow < N_NODES) {
                    int g = batch[nrow];
                    atomicAdd(&s_gsum[g], sum[i]);
                    atomicAdd(&s_gsq[g], sq[i]);
                    atomicAdd(&s_gcnt[g], 1.0f);
                }
            }
        }
    }
    __syncthreads();
    if (tid < G_NUM && s_gcnt[tid] > 0.f) {
        unsafeAtomicAdd(&gstat[tid], s_gsum[tid]);
        unsafeAtomicAdd(&gstat[G_NUM + tid], s_gsq[tid]);
        unsafeAtomicAdd(&gstat[2 * G_NUM + tid], s_gcnt[tid]);
    }
}

// ---------------------------------------------------------------------------
// Graph-LN apply + ReLU (finalize folded in)
// ---------------------------------------------------------------------------
__global__ __launch_bounds__(256) void final_ln_kernel(
    float* __restrict__ h3, const int* __restrict__ batch,
    const float* __restrict__ lnw, const float* __restrict__ lnb,
    const float* __restrict__ gstat)
{
    int idx4 = blockIdx.x * 256 + threadIdx.x;
    if (idx4 >= N_NODES * 32) return;
    int node = idx4 >> 5;
    int c4 = (idx4 & 31) * 4;
    int g = batch[node];
    float s   = gstat[g];
    float qq  = gstat[G_NUM + g];
    float cnt = gstat[2 * G_NUM + g];
    float norm = fmaxf(cnt * (float)H, 1.0f);
    float mean = s / norm;
    float var  = qq / norm - mean * mean;
    float inv  = rsqrtf(var + LN_EPS);
    float4 v = ((const float4*)h3)[idx4];
    float4 w = *(const float4*)&lnw[c4];
    float4 b = *(const float4*)&lnb[c4];
    v.x = fmaxf(0.f, (v.x - mean) * inv * w.x + b.x);
    v.y = fmaxf(0.f, (v.y - mean) * inv * w.y + b.y);
    v.z = fmaxf(0.f, (v.z - mean) * inv * w.z + b.z);
    v.w = fmaxf(0.f, (v.w - mean) * inv * w.w + b.w);
    ((float4*)h3)[idx4] = v;
}

// ---------------------------------------------------------------------------
extern "C" void kernel_launch(void* const* d_in, const int* in_sizes, int n_in,
                              void* d_out, int out_size, void* d_ws, size_t ws_size,
                              hipStream_t stream)
{
    const float* node  = (const float*)d_in[0];
    const int*   ei    = (const int*)d_in[1];
    // d_in[2] = edge_attr (unused)
    const int*   batch = (const int*)d_in[3];
    const float* epsp  = (const float*)d_in[4];
    const float* W1    = (const float*)d_in[5];
    const float* b1    = (const float*)d_in[6];
    const float* g1    = (const float*)d_in[7];
    const float* be1   = (const float*)d_in[8];
    const float* W2    = (const float*)d_in[9];
    const float* b2    = (const float*)d_in[10];
    const float* g2    = (const float*)d_in[11];
    const float* be2   = (const float*)d_in[12];
    const float* W3    = (const float*)d_in[13];
    const float* b3    = (const float*)d_in[14];
    const float* lnw   = (const float*)d_in[15];
    const float* lnb   = (const float*)d_in[16];

    float* out = (float*)d_out;

    int* base = (int*)d_ws;
    float* gstat  = (float*)d_ws;
    int*   deg    = base + 512;
    int*   off    = deg + N_NODES;
    int*   cursor = off + N_NODES + 1;
    int*   csr    = cursor + N_NODES;
    int*   blksum = csr + N_EDGES;
    unsigned short* WT = (unsigned short*)(base + WT_IOFF);      // 16B-aligned

    // h0 placement: with room for a bf16 node table, nbf at NBF_IOFF and h0
    // after it; otherwise h0 takes the NBF slot and the gather reads fp32 node.
    const bool use_bf = (ws_size >= NEEDED_BF);
    unsigned int* nbf = (unsigned int*)(base + NBF_IOFF);
    unsigned int* h0  = use_bf ? (unsigned int*)(base + H0_BF_IOFF)
                               : (unsigned int*)(base + NBF_IOFF);

    // single memset covers gstat (512 floats) + adjacent deg (N ints)
    hipMemsetAsync(d_ws, 0, (512 + N_NODES) * sizeof(int), stream);

    hist_cvt_kernel<<<HIST_NB + (use_bf ? CVT_NB : 0), 256, 0, stream>>>(
        ei, deg, node, nbf);
    scan1_kernel<<<SCAN_NB, 256, 0, stream>>>(deg, off, blksum);
    scan23_kernel<<<(N_NODES + 255) / 256, 256, 0, stream>>>(off, blksum, cursor);
    fill_wt_kernel<<<FILL_NB + WT_NB, 256, 0, stream>>>(ei, cursor, csr,
                                                        W1, W2, W3, WT);

    if (use_bf)
        gather_kernel<true><<<NTILES, 256, 0, stream>>>(node, nbf, off, csr,
                                                        epsp, h0);
    else
        gather_kernel<false><<<NTILES, 256, 0, stream>>>(node, nbf, off, csr,
                                                         epsp, h0);

    mlp_kernel<<<NTILES, 256, 0, stream>>>(h0, WT, b1, g1, be1, b2, g2, be2,
                                           b3, batch, out, gstat);

    final_ln_kernel<<<(N_NODES * 32 + 255) / 256, 256, 0, stream>>>(
        out, batch, lnw, lnb, gstat);
}